// Round 17
// baseline (168.548 us; speedup 1.0000x reference)
//
#include <hip/hip_runtime.h>
#include <hip/hip_fp16.h>

#define BOHR_F 0.5291772105638411f
#define HA_D   27.211386024367243
#define A1_F   0.4289f
#define A2_F   4.4407f
#define S6_F   1.0f
#define S8_F   0.7875f
#define KCN_F  16.0f
#define WF_F   4.0f
#define EPS_F  1.1920929e-07f

#define Q15_SCALE 32767.0f
#define Q15_INV   (1.0f/32767.0f)
#define DR_SCALE  512.0f
#define DR_INV    (1.0f/512.0f)
#define CN_SCALE 8388608.0f
#define CN_INV   (1.0f/8388608.0f)

#define NELEM  95
#define NBLK   512           // hist grid
#define BSW    1024          // hist block
#define T_EDGES 2048         // scatter tile (LDS-staged)
#define BSC    512           // scatter block (27KB LDS -> 4 blocks/CU)

__device__ __forceinline__ float smooth_cutoff(float dr, float r_on, float r_cut) {
    float r_c = r_cut * r_cut;
    float r_o = r_on * r_on;
    float r   = dr * dr;
    float den = (r_c - r_o);
    float t   = r_c - r;
    float inner = (dr < r_cut)
        ? (t * t * (r_c + 2.0f * r - 3.0f * r_o)) / (den * den * den)
        : 0.0f;
    return (dr < r_on) ? 1.0f : inner;
}

__device__ __forceinline__ float edge_m(float dr, float rc) {
    if (!(dr > 0.0f)) return 0.0f;
    float count = 1.0f / (1.0f + expf(-KCN_F * (rc / dr - 1.0f)));
    return smooth_cutoff(dr, 20.0f, 25.0f) * count;
}

__device__ __forceinline__ void u2f2(unsigned u, float& a, float& b) {
    __half2 h = __builtin_bit_cast(__half2, u);
    float2 f = __half22float2(h);
    a = f.x; b = f.y;
}

// per-edge energy: fp16 atom records + u8-quantized c6 row (2 x uint4).
__device__ __forceinline__ float edge_e8(float dr, uint4 Ri, uint4 Rj,
                                         uint4 c0, uint4 c1) {
    float wi[5], wj[5], qi, qj;
    u2f2(Ri.x, wi[0], wi[1]); u2f2(Ri.y, wi[2], wi[3]); u2f2(Ri.z, wi[4], qi);
    u2f2(Rj.x, wj[0], wj[1]); u2f2(Rj.y, wj[2], wj[3]); u2f2(Rj.z, wj[4], qj);
    unsigned w[7] = { c0.x, c0.y, c0.z, c0.w, c1.x, c1.y, c1.z };
    float sc = __uint_as_float(c1.w);
    float c6q = 0.0f;
#pragma unroll
    for (int a = 0; a < 5; ++a) {
#pragma unroll
        for (int b = 0; b < 5; ++b) {
            const int k = a * 5 + b;
            float qv = (float)((w[k >> 2] >> ((k & 3) * 8)) & 0xFFu);
            c6q += wj[a] * wi[b] * qv;
        }
    }
    float c6 = c6q * sc;
    float qq = 3.0f * qi * qj;
    float rr = A1_F * sqrtf(qq) + A2_F;
    float dr2 = dr * dr;
    float dr6 = dr2 * dr2 * dr2;
    float dr8 = dr6 * dr2;
    float rr2 = rr * rr;
    float rr6 = rr2 * rr2 * rr2;
    float rr8 = rr6 * rr2;
    float damped = -c6 * (S6_F / (dr6 + rr6) + S8_F * qq / (dr8 + rr8));
    return smooth_cutoff(dr, 55.0f, 60.0f) * damped * 0.5f;
}

// ---------------- prep ----------------
__global__ __launch_bounds__(256)
void k_prep_c6u8(const float* __restrict__ src, unsigned char* __restrict__ dst,
                 int nrows) {
    int r = blockIdx.x * blockDim.x + threadIdx.x;
    if (r >= nrows) return;
    const float* s = src + (size_t)r * 25;
    float mx = 0.0f;
#pragma unroll
    for (int k = 0; k < 25; ++k) mx = fmaxf(mx, fabsf(s[k]));
    float sc  = mx * (1.0f / 255.0f);
    float inv = (mx > 0.0f) ? 255.0f / mx : 0.0f;
    unsigned w[8];
#pragma unroll
    for (int v = 0; v < 7; ++v) {
        unsigned acc = 0;
#pragma unroll
        for (int b = 0; b < 4; ++b) {
            int k = v * 4 + b;
            unsigned q = 0;
            if (k < 25) {
                float t = s[k] * inv;
                t = fmaxf(t, 0.0f);
                q = (unsigned)(t + 0.5f);
                if (q > 255u) q = 255u;
            }
            acc |= q << (b * 8);
        }
        w[v] = acc;
    }
    w[7] = __float_as_uint(sc);
    uint4* d = reinterpret_cast<uint4*>(dst + (size_t)r * 32);
    d[0] = make_uint4(w[0], w[1], w[2], w[3]);
    d[1] = make_uint4(w[4], w[5], w[6], w[7]);
}

__global__ __launch_bounds__(256)
void k_prep_atom(const int* __restrict__ numbers, const float* __restrict__ rcov,
                 uint2* __restrict__ rcovZ, int n_atoms) {
    int a = blockIdx.x * blockDim.x + threadIdx.x;
    if (a >= n_atoms) return;
    int Z = numbers[a];
    rcovZ[a] = make_uint2(__float_as_uint(rcov[Z]), (unsigned)Z);
}

// ---------------- sort path ----------------
// Pass A: bucket totals (streams idx_i; totals must be pre-zeroed).
__global__ __launch_bounds__(BSW, 4)
void k_hist(const int* __restrict__ idx_i, unsigned* __restrict__ totals,
            int n_edges, int nb) {
    __shared__ unsigned hist[256];
    if (threadIdx.x < 256) hist[threadIdx.x] = 0;
    __syncthreads();
    int nquad = n_edges >> 2;
    int tid = blockIdx.x * blockDim.x + threadIdx.x;
    int stride = gridDim.x * blockDim.x;
    for (int qd = tid; qd < nquad; qd += stride) {
        int4 i4 = *reinterpret_cast<const int4*>(idx_i + (qd << 2));
        atomicAdd(&hist[i4.x >> 9], 1u);
        atomicAdd(&hist[i4.y >> 9], 1u);
        atomicAdd(&hist[i4.z >> 9], 1u);
        atomicAdd(&hist[i4.w >> 9], 1u);
    }
    for (int e = (nquad << 2) + tid; e < n_edges; e += stride)
        atomicAdd(&hist[idx_i[e] >> 9], 1u);
    __syncthreads();
    if ((int)threadIdx.x < nb && hist[threadIdx.x])
        atomicAdd(&totals[threadIdx.x], hist[threadIdx.x]);
}

// Pass B: exclusive scan over totals -> base[nb+1]; cursor[b] = base[b].
__global__ __launch_bounds__(256)
void k_scan_base(const unsigned* __restrict__ totals,
                 unsigned* __restrict__ base,
                 unsigned* __restrict__ cursor, int nb) {
    __shared__ unsigned s[256];
    int t = threadIdx.x;
    unsigned v = (t < nb) ? totals[t] : 0u;
    s[t] = v;
    __syncthreads();
    for (int off = 1; off < 256; off <<= 1) {
        unsigned x = (t >= off) ? s[t - off] : 0u;
        __syncthreads();
        s[t] += x;
        __syncthreads();
    }
    if (t < nb) {
        unsigned ex = s[t] - v;
        base[t] = ex;
        cursor[t] = ex;
    }
    if (t == 255) base[nb] = s[t];
}

// Pass C: LDS-staged scatter — per-tile bucket sort in LDS, then coalesced
// run writes. 2048-edge tiles @ 512 threads keep LDS at ~27KB so 4 blocks/CU
// are resident to overlap the barrier-separated phases (R16 lesson: 52KB
// tiles -> 2 blocks/CU -> barrier stalls dominate).
template<bool ZS>
__global__ __launch_bounds__(BSC)
void k_scatter_lds(const float* __restrict__ dr_vec,
                   const int* __restrict__ idx_i,
                   const int* __restrict__ idx_j,
                   const uint2* __restrict__ rcovZ,
                   unsigned* __restrict__ cursor,
                   uint2* __restrict__ pairs,
                   unsigned* __restrict__ zbuf,
                   int n_edges) {
    __shared__ unsigned hcnt[256];
    __shared__ unsigned tincl[256];    // inclusive scan of hcnt
    __shared__ unsigned runstart[256]; // global run base minus tile-local start
    __shared__ unsigned sw0[T_EDGES];
    __shared__ unsigned sw1[T_EDGES];
    __shared__ unsigned sz[T_EDGES];

    int t0 = blockIdx.x * T_EDGES;
    int cnt = n_edges - t0;
    if (cnt <= 0) return;
    if (cnt > T_EDGES) cnt = T_EDGES;

    if (threadIdx.x < 256) hcnt[threadIdx.x] = 0;
    __syncthreads();

    // phase 1: compute 4 consecutive edges, count ranks
    int e0 = t0 + ((int)threadIdx.x << 2);
    unsigned w0a[4], w1a[4], zpa[4], rk[4];
    int bk[4];
    int ne = n_edges - e0;
    if (ne < 0) ne = 0;
    if (ne > 4) ne = 4;
    if (ne == 4) {
        float4 v0 = *reinterpret_cast<const float4*>(dr_vec + 3 * e0);
        float4 v1 = *reinterpret_cast<const float4*>(dr_vec + 3 * e0 + 4);
        float4 v2 = *reinterpret_cast<const float4*>(dr_vec + 3 * e0 + 8);
        float drq[4];
        drq[0] = sqrtf(v0.x*v0.x + v0.y*v0.y + v0.z*v0.z) / BOHR_F;
        drq[1] = sqrtf(v0.w*v0.w + v1.x*v1.x + v1.y*v1.y) / BOHR_F;
        drq[2] = sqrtf(v1.z*v1.z + v1.w*v1.w + v2.x*v2.x) / BOHR_F;
        drq[3] = sqrtf(v2.y*v2.y + v2.z*v2.z + v2.w*v2.w) / BOHR_F;
        int4 i4 = *reinterpret_cast<const int4*>(idx_i + e0);
        int4 j4 = *reinterpret_cast<const int4*>(idx_j + e0);
        int ia[4] = { i4.x, i4.y, i4.z, i4.w };
        int ja[4] = { j4.x, j4.y, j4.z, j4.w };
        uint2 RiZ[4], RjZ[4];
#pragma unroll
        for (int k = 0; k < 4; ++k) { RiZ[k] = rcovZ[ia[k]]; RjZ[k] = rcovZ[ja[k]]; }
#pragma unroll
        for (int k = 0; k < 4; ++k) {
            float rc = __uint_as_float(RiZ[k].x) + __uint_as_float(RjZ[k].x);
            float m = edge_m(drq[k], rc);
            unsigned q = (unsigned)(m * Q15_SCALE + 0.5f);
            if (q > 0x7FFFu) q = 0x7FFFu;
            unsigned dq = (unsigned)(drq[k] * DR_SCALE + 0.5f);
            if (dq > 0x7FFFu) dq = 0x7FFFu;
            w0a[k] = ((unsigned)ia[k] << 15) | q;
            w1a[k] = ((unsigned)ja[k] << 15) | dq;
            zpa[k] = RjZ[k].y * NELEM + RiZ[k].y;
            bk[k]  = ia[k] >> 9;
            rk[k]  = atomicAdd(&hcnt[bk[k]], 1u);
        }
    } else {
        for (int k = 0; k < ne; ++k) {
            int e = e0 + k;
            float x = dr_vec[3*e], y = dr_vec[3*e+1], z = dr_vec[3*e+2];
            float dr = sqrtf(x*x + y*y + z*z) / BOHR_F;
            int i = idx_i[e], j = idx_j[e];
            uint2 RiZ = rcovZ[i], RjZ = rcovZ[j];
            float m = edge_m(dr, __uint_as_float(RiZ.x) + __uint_as_float(RjZ.x));
            unsigned q = (unsigned)(m * Q15_SCALE + 0.5f);
            if (q > 0x7FFFu) q = 0x7FFFu;
            unsigned dq = (unsigned)(dr * DR_SCALE + 0.5f);
            if (dq > 0x7FFFu) dq = 0x7FFFu;
            w0a[k] = ((unsigned)i << 15) | q;
            w1a[k] = ((unsigned)j << 15) | dq;
            zpa[k] = RjZ.y * NELEM + RiZ.y;
            bk[k]  = i >> 9;
            rk[k]  = atomicAdd(&hcnt[bk[k]], 1u);
        }
    }
    __syncthreads();

    // phase 2: inclusive scan of hcnt -> tincl
    if (threadIdx.x < 256) tincl[threadIdx.x] = hcnt[threadIdx.x];
    __syncthreads();
    for (int off = 1; off < 256; off <<= 1) {
        unsigned v = 0;
        if (threadIdx.x < 256 && (int)threadIdx.x >= off)
            v = tincl[threadIdx.x - off];
        __syncthreads();
        if (threadIdx.x < 256) tincl[threadIdx.x] += v;
        __syncthreads();
    }
    // claim global runs; runstart[b] = global_base_of_run - tile_local_start
    if (threadIdx.x < 256) {
        unsigned h = hcnt[threadIdx.x];
        unsigned g = h ? atomicAdd(&cursor[threadIdx.x], h) : 0u;
        runstart[threadIdx.x] = g - (tincl[threadIdx.x] - h);
    }
    __syncthreads();

    // phase 3: stage into LDS, bucket-sorted
    for (int k = 0; k < ne; ++k) {
        unsigned s = tincl[bk[k]] - hcnt[bk[k]] + rk[k];
        sw0[s] = w0a[k];
        sw1[s] = w1a[k];
        if (ZS) sz[s] = zpa[k];
    }
    __syncthreads();

    // phase 4: coalesced copy-out; bucket read straight from sw0's top bits.
    for (int s = threadIdx.x; s < cnt; s += BSC) {
        unsigned w0 = sw0[s];
        unsigned dst = runstart[w0 >> 24] + (unsigned)s;
        pairs[dst] = make_uint2(w0, sw1[s]);
        if (ZS) zbuf[dst] = sz[s];
    }
}

// Pass D: per-bucket LDS reduce -> cn; fused weights -> rec {w0..4, r4r2, Z, 0}
__global__ __launch_bounds__(512)
void k_reduce_weights(const uint2* __restrict__ pairs,
                      const unsigned* __restrict__ base,
                      const int* __restrict__ numbers,
                      const float* __restrict__ ref_cn_table,
                      const float* __restrict__ r4r2,
                      __half* __restrict__ rec,
                      int n_atoms) {
    __shared__ unsigned hist[512];
    hist[threadIdx.x] = 0;
    __syncthreads();
    int b = blockIdx.x;
    unsigned start = base[b];
    unsigned end   = base[b + 1];
    for (unsigned k = start + threadIdx.x; k < end; k += 512) {
        unsigned p = pairs[k].x;
        atomicAdd(&hist[(p >> 15) & 511], p & 0x7FFFu);
    }
    __syncthreads();
    int a = (b << 9) + threadIdx.x;
    if (a < n_atoms) {
        float c = (float)hist[threadIdx.x] * Q15_INV;
        int Z = numbers[a];
        float w[5];
        float s = 0.0f;
#pragma unroll
        for (int r = 0; r < 5; ++r) {
            float rcn = ref_cn_table[Z * 5 + r];
            float d = rcn - c;
            float wv = (rcn >= 0.0f) ? expf(-WF_F * d * d) : 0.0f;
            w[r] = wv;
            s += wv;
        }
        float den = s + EPS_F;
        __half* rr = rec + (size_t)a * 8;
#pragma unroll
        for (int r = 0; r < 5; ++r) rr[r] = __float2half(w[r] / den);
        rr[5] = __float2half(r4r2[Z]);
        rr[6] = __float2half((float)Z);
        rr[7] = __float2half(0.0f);
    }
}

// ---------------- energy (sorted, 8 edges/thread, zbuf stream) ----------------
#define LOADC8(p, z) do { \
    const uint4* _cp = reinterpret_cast<const uint4*>(c6q + (size_t)(z) * 32); \
    p##0 = _cp[0]; p##1 = _cp[1]; } while (0)

__global__ __launch_bounds__(256)
void k_energy_sorted8(const uint2* __restrict__ pairs,
                      const unsigned* __restrict__ zbuf,
                      const __half* __restrict__ rec,         // [N,8] halfs
                      const unsigned char* __restrict__ c6q,  // [95*95][32B]
                      double* __restrict__ e_acc,
                      int n_edges) {
    double local = 0.0;
    const uint4* recv = reinterpret_cast<const uint4*>(rec);
    int noct = n_edges >> 3;
    int tid = blockIdx.x * blockDim.x + threadIdx.x;
    int stride = gridDim.x * blockDim.x;
    for (int oc = tid; oc < noct; oc += stride) {
        int e0 = oc << 3;
        const uint4* pp = reinterpret_cast<const uint4*>(pairs + e0);
        uint4 p0 = pp[0], p1 = pp[1], p2 = pp[2], p3 = pp[3];
        const uint4* zz = reinterpret_cast<const uint4*>(zbuf + e0);
        uint4 z0 = zz[0], z1 = zz[1];
        unsigned iA = p0.x >> 15, jA = p0.y >> 15;
        unsigned iB = p0.z >> 15, jB = p0.w >> 15;
        unsigned iC = p1.x >> 15, jC = p1.y >> 15;
        unsigned iD = p1.z >> 15, jD = p1.w >> 15;
        unsigned iE = p2.x >> 15, jE = p2.y >> 15;
        unsigned iF = p2.z >> 15, jF = p2.w >> 15;
        unsigned iG = p3.x >> 15, jG = p3.y >> 15;
        unsigned iH = p3.z >> 15, jH = p3.w >> 15;
        float drA = (float)(p0.y & 0x7FFFu) * DR_INV;
        float drB = (float)(p0.w & 0x7FFFu) * DR_INV;
        float drC = (float)(p1.y & 0x7FFFu) * DR_INV;
        float drD = (float)(p1.w & 0x7FFFu) * DR_INV;
        float drE = (float)(p2.y & 0x7FFFu) * DR_INV;
        float drF = (float)(p2.w & 0x7FFFu) * DR_INV;
        float drG = (float)(p3.y & 0x7FFFu) * DR_INV;
        float drH = (float)(p3.w & 0x7FFFu) * DR_INV;
        int zpA = (int)z0.x, zpB = (int)z0.y;
        int zpC = (int)z0.z, zpD = (int)z0.w;
        int zpE = (int)z1.x, zpF = (int)z1.y;
        int zpG = (int)z1.z, zpH = (int)z1.w;
        uint4 cA0, cA1;  LOADC8(cA, zpA);
        uint4 cB0, cB1;  LOADC8(cB, zpB);
        uint4 cC0, cC1;  LOADC8(cC, zpC);
        uint4 cD0, cD1;  LOADC8(cD, zpD);
        uint4 cE0, cE1;  LOADC8(cE, zpE);
        uint4 cF0, cF1;  LOADC8(cF, zpF);
        uint4 cG0, cG1;  LOADC8(cG, zpG);
        uint4 cH0, cH1;  LOADC8(cH, zpH);
        uint4 RiA = recv[iA], RjA = recv[jA];
        uint4 RiB = recv[iB], RjB = recv[jB];
        uint4 RiC = recv[iC], RjC = recv[jC];
        uint4 RiD = recv[iD], RjD = recv[jD];
        uint4 RiE = recv[iE], RjE = recv[jE];
        uint4 RiF = recv[iF], RjF = recv[jF];
        uint4 RiG = recv[iG], RjG = recv[jG];
        uint4 RiH = recv[iH], RjH = recv[jH];
        local += (double)edge_e8(drA, RiA, RjA, cA0, cA1);
        local += (double)edge_e8(drB, RiB, RjB, cB0, cB1);
        local += (double)edge_e8(drC, RiC, RjC, cC0, cC1);
        local += (double)edge_e8(drD, RiD, RjD, cD0, cD1);
        local += (double)edge_e8(drE, RiE, RjE, cE0, cE1);
        local += (double)edge_e8(drF, RiF, RjF, cF0, cF1);
        local += (double)edge_e8(drG, RiG, RjG, cG0, cG1);
        local += (double)edge_e8(drH, RiH, RjH, cH0, cH1);
    }
    for (int e = (noct << 3) + tid; e < n_edges; e += stride) {
        uint2 pr = pairs[e];
        unsigned i = pr.x >> 15;
        unsigned j = pr.y >> 15;
        float dr = (float)(pr.y & 0x7FFFu) * DR_INV;
        uint4 Ri = recv[i];
        uint4 Rj = recv[j];
        int zp = (int)zbuf[e];
        const uint4* cp = reinterpret_cast<const uint4*>(c6q + (size_t)zp * 32);
        local += (double)edge_e8(dr, Ri, Rj, cp[0], cp[1]);
    }

    __shared__ double sdata[4];
    for (int off = 32; off > 0; off >>= 1)
        local += __shfl_down(local, off, 64);
    int lane = threadIdx.x & 63;
    int wid  = threadIdx.x >> 6;
    if (lane == 0) sdata[wid] = local;
    __syncthreads();
    if (threadIdx.x == 0) {
        double s = sdata[0] + sdata[1] + sdata[2] + sdata[3];
        atomicAdd(e_acc, s);
    }
}

__device__ __forceinline__ int zfromR(uint4 R) {
    float z, dum;
    u2f2(R.w, z, dum);
    return (int)z;
}

// tier-2 energy (no zbuf): 4-edge batch, Z from rec.
__global__ __launch_bounds__(256, 1)
void k_energy_sorted4(const uint2* __restrict__ pairs,
                      const __half* __restrict__ rec,
                      const unsigned char* __restrict__ c6q,
                      double* __restrict__ e_acc,
                      int n_edges) {
    double local = 0.0;
    const uint4* recv = reinterpret_cast<const uint4*>(rec);
    int nquad = n_edges >> 2;
    int tid = blockIdx.x * blockDim.x + threadIdx.x;
    int stride = gridDim.x * blockDim.x;
    for (int qd = tid; qd < nquad; qd += stride) {
        int e0 = qd << 2;
        uint4 pA = *reinterpret_cast<const uint4*>(pairs + e0);
        uint4 pB = *reinterpret_cast<const uint4*>(pairs + e0 + 2);
        unsigned i0 = pA.x >> 15, j0 = pA.y >> 15;
        unsigned i1 = pA.z >> 15, j1 = pA.w >> 15;
        unsigned i2 = pB.x >> 15, j2 = pB.y >> 15;
        unsigned i3 = pB.z >> 15, j3 = pB.w >> 15;
        float dr0 = (float)(pA.y & 0x7FFFu) * DR_INV;
        float dr1 = (float)(pA.w & 0x7FFFu) * DR_INV;
        float dr2 = (float)(pB.y & 0x7FFFu) * DR_INV;
        float dr3 = (float)(pB.w & 0x7FFFu) * DR_INV;
        uint4 Ri0 = recv[i0], Rj0 = recv[j0];
        uint4 Ri1 = recv[i1], Rj1 = recv[j1];
        uint4 Ri2 = recv[i2], Rj2 = recv[j2];
        uint4 Ri3 = recv[i3], Rj3 = recv[j3];
        int zp0 = zfromR(Rj0) * NELEM + zfromR(Ri0);
        int zp1 = zfromR(Rj1) * NELEM + zfromR(Ri1);
        int zp2 = zfromR(Rj2) * NELEM + zfromR(Ri2);
        int zp3 = zfromR(Rj3) * NELEM + zfromR(Ri3);
        uint4 a0, a1;   LOADC8(a, zp0);
        uint4 b0, b1;   LOADC8(b, zp1);
        uint4 c0, c1;   LOADC8(c, zp2);
        uint4 d0, d1;   LOADC8(d, zp3);
        local += (double)edge_e8(dr0, Ri0, Rj0, a0, a1);
        local += (double)edge_e8(dr1, Ri1, Rj1, b0, b1);
        local += (double)edge_e8(dr2, Ri2, Rj2, c0, c1);
        local += (double)edge_e8(dr3, Ri3, Rj3, d0, d1);
    }
    for (int e = (nquad << 2) + tid; e < n_edges; e += stride) {
        uint2 pr = pairs[e];
        unsigned i = pr.x >> 15;
        unsigned j = pr.y >> 15;
        float dr = (float)(pr.y & 0x7FFFu) * DR_INV;
        uint4 Ri = recv[i];
        uint4 Rj = recv[j];
        int zp = zfromR(Rj) * NELEM + zfromR(Ri);
        const uint4* cp = reinterpret_cast<const uint4*>(c6q + (size_t)zp * 32);
        local += (double)edge_e8(dr, Ri, Rj, cp[0], cp[1]);
    }
    __shared__ double sdata[4];
    for (int off = 32; off > 0; off >>= 1)
        local += __shfl_down(local, off, 64);
    int lane = threadIdx.x & 63;
    int wid  = threadIdx.x >> 6;
    if (lane == 0) sdata[wid] = local;
    __syncthreads();
    if (threadIdx.x == 0) {
        double s = sdata[0] + sdata[1] + sdata[2] + sdata[3];
        atomicAdd(e_acc, s);
    }
}

// ---------------- atomic fallback path (small ws only) ----------------
__global__ __launch_bounds__(256)
void k_edges_cn_atomic(const float* __restrict__ dr_vec,
                       const int* __restrict__ idx_i,
                       const int* __restrict__ idx_j,
                       const uint2* __restrict__ rcovZ,
                       unsigned* __restrict__ cn_u32,
                       int n_edges) {
    int e = blockIdx.x * blockDim.x + threadIdx.x;
    if (e >= n_edges) return;
    float x = dr_vec[3 * e + 0];
    float y = dr_vec[3 * e + 1];
    float z = dr_vec[3 * e + 2];
    float dr = sqrtf(x * x + y * y + z * z) / BOHR_F;
    int i = idx_i[e];
    int j = idx_j[e];
    uint2 RiZ = rcovZ[i], RjZ = rcovZ[j];
    float m = edge_m(dr, __uint_as_float(RiZ.x) + __uint_as_float(RjZ.x));
    unsigned q = (unsigned)(m * CN_SCALE + 0.5f);
    if (q) atomicAdd(&cn_u32[i], q);
}

__global__ __launch_bounds__(256)
void k_atom_weights_rec(const unsigned* __restrict__ cn_u32,
                        const int* __restrict__ numbers,
                        const float* __restrict__ ref_cn_table,
                        const float* __restrict__ r4r2,
                        __half* __restrict__ rec,
                        int n_atoms) {
    int a = blockIdx.x * blockDim.x + threadIdx.x;
    if (a >= n_atoms) return;
    float c = (float)cn_u32[a] * CN_INV;
    int Z = numbers[a];
    float w[5];
    float s = 0.0f;
#pragma unroll
    for (int r = 0; r < 5; ++r) {
        float rcn = ref_cn_table[Z * 5 + r];
        float d = rcn - c;
        float wv = (rcn >= 0.0f) ? expf(-WF_F * d * d) : 0.0f;
        w[r] = wv;
        s += wv;
    }
    float den = s + EPS_F;
    __half* rr = rec + (size_t)a * 8;
#pragma unroll
    for (int r = 0; r < 5; ++r) rr[r] = __float2half(w[r] / den);
    rr[5] = __float2half(r4r2[Z]);
    rr[6] = __float2half((float)Z);
    rr[7] = __float2half(0.0f);
}

__global__ __launch_bounds__(256)
void k_energy_unsorted(const float* __restrict__ dr_vec,
                       const int* __restrict__ idx_i,
                       const int* __restrict__ idx_j,
                       const __half* __restrict__ rec,
                       const unsigned char* __restrict__ c6q,
                       double* __restrict__ e_acc,
                       int n_edges) {
    double local = 0.0;
    const uint4* recv = reinterpret_cast<const uint4*>(rec);
    int tid = blockIdx.x * blockDim.x + threadIdx.x;
    int stride = gridDim.x * blockDim.x;
    for (int e = tid; e < n_edges; e += stride) {
        float x = dr_vec[3*e], y = dr_vec[3*e+1], z = dr_vec[3*e+2];
        float dr = sqrtf(x*x + y*y + z*z) / BOHR_F;
        int i = idx_i[e], j = idx_j[e];
        uint4 Ri = recv[i];
        uint4 Rj = recv[j];
        int zp = zfromR(Rj) * NELEM + zfromR(Ri);
        const uint4* cp = reinterpret_cast<const uint4*>(c6q + (size_t)zp * 32);
        local += (double)edge_e8(dr, Ri, Rj, cp[0], cp[1]);
    }
    __shared__ double sdata[4];
    for (int off = 32; off > 0; off >>= 1)
        local += __shfl_down(local, off, 64);
    int lane = threadIdx.x & 63;
    int wid  = threadIdx.x >> 6;
    if (lane == 0) sdata[wid] = local;
    __syncthreads();
    if (threadIdx.x == 0) {
        double s = sdata[0] + sdata[1] + sdata[2] + sdata[3];
        atomicAdd(e_acc, s);
    }
}

__global__ void k_finalize(const double* __restrict__ e_acc,
                           float* __restrict__ out) {
    out[0] = (float)(e_acc[0] * HA_D);
}

static inline size_t a16(size_t x) { return (x + 15) & ~(size_t)15; }

extern "C" void kernel_launch(void* const* d_in, const int* in_sizes, int n_in,
                              void* d_out, int out_size, void* d_ws, size_t ws_size,
                              hipStream_t stream) {
    const float* dr_vec      = (const float*)d_in[0];
    const float* ref_cn_tab  = (const float*)d_in[1];
    const float* ref_c6_tab  = (const float*)d_in[2];
    const float* r4r2        = (const float*)d_in[3];
    const float* rcov        = (const float*)d_in[4];
    const int*   numbers     = (const int*)d_in[5];
    const int*   idx         = (const int*)d_in[6];

    int n_atoms = in_sizes[5];
    int n_edges = in_sizes[6] / 2;
    const int* idx_i = idx;
    const int* idx_j = idx + n_edges;

    const int BS = 256;
    int nb = (n_atoms + 511) >> 9;
    int nrows = NELEM * NELEM;

    char* ws = (char*)d_ws;
    double* e_acc = (double*)ws;

    // common prefix: [e_acc 16][rec N*16B][c6q rows*32B][rcovZ N*8]
    size_t off_rec = 16;
    size_t off_c6q = a16(off_rec + (size_t)n_atoms * 8 * 2);
    size_t off_rcZ = a16(off_c6q + (size_t)nrows * 32);
    size_t off_var = a16(off_rcZ + (size_t)n_atoms * 8);

    // tier1: [pairs 8E][zbuf 4E][totals 256][base nb+1][cursor nb]
    size_t t1_pairs = off_var;
    size_t t1_zb    = a16(t1_pairs + (size_t)n_edges * 8);
    size_t t1_tot   = a16(t1_zb + (size_t)n_edges * 4);
    size_t t1_base  = a16(t1_tot + 256 * 4);
    size_t t1_cur   = a16(t1_base + (size_t)(nb + 1) * 4);
    size_t need_t1  = t1_cur + (size_t)nb * 4;

    // tier2: [pairs 8E][totals][base][cursor]
    size_t t2_pairs = off_var;
    size_t t2_tot   = a16(t2_pairs + (size_t)n_edges * 8);
    size_t t2_base  = a16(t2_tot + 256 * 4);
    size_t t2_cur   = a16(t2_base + (size_t)(nb + 1) * 4);
    size_t need_t2  = t2_cur + (size_t)nb * 4;

    // tier3 (atomic): [cn N*4]
    size_t a_cn = off_var;

    int grid_r  = (nrows + BS - 1) / BS;
    int grid_a  = (n_atoms + BS - 1) / BS;
    int ntile   = (n_edges + T_EDGES - 1) / T_EDGES;
    int noct    = n_edges >> 3;
    int grid_o  = (noct + BS - 1) / BS;
    if (grid_o < 1) grid_o = 1;
    if (grid_o > 8192) grid_o = 8192;
    int nquad   = (n_edges + 3) >> 2;
    int grid_q  = (nquad + BS - 1) / BS;
    if (grid_q > 8192) grid_q = 8192;
    int grid_e1 = (n_edges + BS - 1) / BS;
    if (grid_e1 > 8192) grid_e1 = 8192;

    __half*        rec   = (__half*)(ws + off_rec);
    unsigned char* c6q   = (unsigned char*)(ws + off_c6q);
    uint2*         rcovZ = (uint2*)(ws + off_rcZ);

    k_prep_c6u8<<<grid_r, BS, 0, stream>>>(ref_c6_tab, c6q, nrows);
    k_prep_atom<<<grid_a, BS, 0, stream>>>(numbers, rcov, rcovZ, n_atoms);

    bool sortable = (n_atoms <= (1 << 17)) && (nb <= 256);

    if (sortable && ws_size >= need_t2) {
        bool zsOK = (ws_size >= need_t1);
        uint2*    pairs  = (uint2*)(ws + (zsOK ? t1_pairs : t2_pairs));
        unsigned* zbuf   = zsOK ? (unsigned*)(ws + t1_zb) : nullptr;
        unsigned* totals = (unsigned*)(ws + (zsOK ? t1_tot : t2_tot));
        unsigned* base   = (unsigned*)(ws + (zsOK ? t1_base : t2_base));
        unsigned* cursor = (unsigned*)(ws + (zsOK ? t1_cur : t2_cur));

        hipMemsetAsync(d_ws, 0, 16, stream);             // e_acc
        hipMemsetAsync(totals, 0, 256 * 4, stream);      // bucket totals

        k_hist<<<NBLK, BSW, 0, stream>>>(idx_i, totals, n_edges, nb);
        k_scan_base<<<1, 256, 0, stream>>>(totals, base, cursor, nb);
        if (zsOK)
            k_scatter_lds<true><<<ntile, BSC, 0, stream>>>(dr_vec, idx_i,
                idx_j, rcovZ, cursor, pairs, zbuf, n_edges);
        else
            k_scatter_lds<false><<<ntile, BSC, 0, stream>>>(dr_vec, idx_i,
                idx_j, rcovZ, cursor, pairs, nullptr, n_edges);
        k_reduce_weights<<<nb, 512, 0, stream>>>(pairs, base, numbers,
            ref_cn_tab, r4r2, rec, n_atoms);
        if (zsOK)
            k_energy_sorted8<<<grid_o, BS, 0, stream>>>(pairs, zbuf, rec, c6q,
                e_acc, n_edges);
        else
            k_energy_sorted4<<<grid_q, BS, 0, stream>>>(pairs, rec, c6q,
                e_acc, n_edges);
    } else {
        unsigned* cn_u32 = (unsigned*)(ws + a_cn);
        hipMemsetAsync(d_ws, 0, 16, stream);
        hipMemsetAsync(cn_u32, 0, (size_t)n_atoms * 4, stream);

        int grid_e = (n_edges + BS - 1) / BS;
        k_edges_cn_atomic<<<grid_e, BS, 0, stream>>>(dr_vec, idx_i, idx_j,
            rcovZ, cn_u32, n_edges);
        k_atom_weights_rec<<<grid_a, BS, 0, stream>>>(cn_u32, numbers,
            ref_cn_tab, r4r2, rec, n_atoms);
        k_energy_unsorted<<<grid_e1, BS, 0, stream>>>(dr_vec, idx_i, idx_j,
            rec, c6q, e_acc, n_edges);
    }

    k_finalize<<<1, 1, 0, stream>>>(e_acc, (float*)d_out);
}

// Round 18
// 129.826 us; speedup vs baseline: 1.2983x; 1.2983x over previous
//
#include <hip/hip_runtime.h>
#include <hip/hip_fp16.h>

#define BOHR_F 0.5291772105638411f
#define HA_D   27.211386024367243
#define A1_F   0.4289f
#define A2_F   4.4407f
#define S6_F   1.0f
#define S8_F   0.7875f
#define KCN_F  16.0f
#define WF_F   4.0f
#define EPS_F  1.1920929e-07f

#define Q15_SCALE 32767.0f
#define Q15_INV   (1.0f/32767.0f)
#define DR_SCALE  512.0f
#define DR_INV    (1.0f/512.0f)
#define CN_SCALE 8388608.0f
#define CN_INV   (1.0f/8388608.0f)

#define NELEM  95
#define NBLK   512           // hist/scatter grid (must match between the two)
#define BSW    512           // hist/scatter block

__device__ __forceinline__ float smooth_cutoff(float dr, float r_on, float r_cut) {
    float r_c = r_cut * r_cut;
    float r_o = r_on * r_on;
    float r   = dr * dr;
    float den = (r_c - r_o);
    float t   = r_c - r;
    float inner = (dr < r_cut)
        ? (t * t * (r_c + 2.0f * r - 3.0f * r_o)) / (den * den * den)
        : 0.0f;
    return (dr < r_on) ? 1.0f : inner;
}

__device__ __forceinline__ float edge_m(float dr, float rc) {
    if (!(dr > 0.0f)) return 0.0f;
    float count = 1.0f / (1.0f + expf(-KCN_F * (rc / dr - 1.0f)));
    return smooth_cutoff(dr, 20.0f, 25.0f) * count;
}

__device__ __forceinline__ void u2f2(unsigned u, float& a, float& b) {
    __half2 h = __builtin_bit_cast(__half2, u);
    float2 f = __half22float2(h);
    a = f.x; b = f.y;
}

// per-edge energy: fp16 atom records + u8-quantized c6 row (2 x uint4).
// c6 row layout (32B): bytes 0..24 = u8 quant, 25..27 pad, 28..31 = f32 scale.
__device__ __forceinline__ float edge_e8(float dr, uint4 Ri, uint4 Rj,
                                         uint4 c0, uint4 c1) {
    float wi[5], wj[5], qi, qj;
    u2f2(Ri.x, wi[0], wi[1]); u2f2(Ri.y, wi[2], wi[3]); u2f2(Ri.z, wi[4], qi);
    u2f2(Rj.x, wj[0], wj[1]); u2f2(Rj.y, wj[2], wj[3]); u2f2(Rj.z, wj[4], qj);
    unsigned w[7] = { c0.x, c0.y, c0.z, c0.w, c1.x, c1.y, c1.z };
    float sc = __uint_as_float(c1.w);
    float c6q = 0.0f;
#pragma unroll
    for (int a = 0; a < 5; ++a) {
#pragma unroll
        for (int b = 0; b < 5; ++b) {
            const int k = a * 5 + b;
            float qv = (float)((w[k >> 2] >> ((k & 3) * 8)) & 0xFFu);
            c6q += wj[a] * wi[b] * qv;
        }
    }
    float c6 = c6q * sc;
    float qq = 3.0f * qi * qj;
    float rr = A1_F * sqrtf(qq) + A2_F;
    float dr2 = dr * dr;
    float dr6 = dr2 * dr2 * dr2;
    float dr8 = dr6 * dr2;
    float rr2 = rr * rr;
    float rr6 = rr2 * rr2 * rr2;
    float rr8 = rr6 * rr2;
    float damped = -c6 * (S6_F / (dr6 + rr6) + S8_F * qq / (dr8 + rr8));
    return smooth_cutoff(dr, 55.0f, 60.0f) * damped * 0.5f;
}

__device__ __forceinline__ int zfromR(uint4 R) {
    float z, dum;
    u2f2(R.w, z, dum);
    return (int)z;
}

// ---------------- prep ----------------
// quantize ref_c6 rows: [95*95][25] f32 -> [95*95][32B] {25 u8, pad, f32 scale}
__global__ __launch_bounds__(256)
void k_prep_c6u8(const float* __restrict__ src, unsigned char* __restrict__ dst,
                 int nrows) {
    int r = blockIdx.x * blockDim.x + threadIdx.x;
    if (r >= nrows) return;
    const float* s = src + (size_t)r * 25;
    float mx = 0.0f;
#pragma unroll
    for (int k = 0; k < 25; ++k) mx = fmaxf(mx, fabsf(s[k]));
    float sc  = mx * (1.0f / 255.0f);
    float inv = (mx > 0.0f) ? 255.0f / mx : 0.0f;
    unsigned w[8];
#pragma unroll
    for (int v = 0; v < 7; ++v) {
        unsigned acc = 0;
#pragma unroll
        for (int b = 0; b < 4; ++b) {
            int k = v * 4 + b;
            unsigned q = 0;
            if (k < 25) {
                float t = s[k] * inv;
                t = fmaxf(t, 0.0f);
                q = (unsigned)(t + 0.5f);
                if (q > 255u) q = 255u;
            }
            acc |= q << (b * 8);
        }
        w[v] = acc;
    }
    w[7] = __float_as_uint(sc);
    uint4* d = reinterpret_cast<uint4*>(dst + (size_t)r * 32);
    d[0] = make_uint4(w[0], w[1], w[2], w[3]);
    d[1] = make_uint4(w[4], w[5], w[6], w[7]);
}

// rcovZ[a] = {f32 rcov[numbers[a]], u32 numbers[a]}
__global__ __launch_bounds__(256)
void k_prep_atom(const int* __restrict__ numbers, const float* __restrict__ rcov,
                 uint2* __restrict__ rcovZ, int n_atoms) {
    int a = blockIdx.x * blockDim.x + threadIdx.x;
    if (a >= n_atoms) return;
    int Z = numbers[a];
    rcovZ[a] = make_uint2(__float_as_uint(rcov[Z]), (unsigned)Z);
}

// ---------------- sort path ----------------
// Pass A: histogram only (streams idx_i). MUST share grid/block + edge
// mapping with k_scatter_full.
__global__ __launch_bounds__(BSW, 4)
void k_hist(const int* __restrict__ idx_i, unsigned* __restrict__ ghist,
            int n_edges, int nb) {
    __shared__ unsigned hist[256];
    if (threadIdx.x < 256) hist[threadIdx.x] = 0;
    __syncthreads();
    int nquad = n_edges >> 2;
    int tid = blockIdx.x * blockDim.x + threadIdx.x;
    int stride = gridDim.x * blockDim.x;
    for (int qd = tid; qd < nquad; qd += stride) {
        int4 i4 = *reinterpret_cast<const int4*>(idx_i + (qd << 2));
        atomicAdd(&hist[i4.x >> 9], 1u);
        atomicAdd(&hist[i4.y >> 9], 1u);
        atomicAdd(&hist[i4.z >> 9], 1u);
        atomicAdd(&hist[i4.w >> 9], 1u);
    }
    for (int e = (nquad << 2) + tid; e < n_edges; e += stride)
        atomicAdd(&hist[idx_i[e] >> 9], 1u);
    __syncthreads();
    if ((int)threadIdx.x < nb)
        ghist[(size_t)threadIdx.x * gridDim.x + blockIdx.x] = hist[threadIdx.x];
}

// Pass B1: per-bucket exclusive scan across NBLK block-counts; bucket totals.
__global__ __launch_bounds__(NBLK)
void k_scan_bucket(unsigned* __restrict__ ghist, unsigned* __restrict__ totals) {
    __shared__ unsigned s[NBLK];
    int b = blockIdx.x;
    int t = threadIdx.x;
    unsigned v = ghist[(size_t)b * NBLK + t];
    s[t] = v;
    __syncthreads();
    for (int off = 1; off < NBLK; off <<= 1) {
        unsigned x = (t >= off) ? s[t - off] : 0u;
        __syncthreads();
        s[t] += x;
        __syncthreads();
    }
    ghist[(size_t)b * NBLK + t] = s[t] - v;   // exclusive
    if (t == NBLK - 1) totals[b] = s[t];
}

// Pass B2: exclusive scan over bucket totals -> base[nb+1].
__global__ __launch_bounds__(256)
void k_scan_base(const unsigned* __restrict__ totals,
                 unsigned* __restrict__ base, int nb) {
    __shared__ unsigned s[256];
    int t = threadIdx.x;
    unsigned v = (t < nb) ? totals[t] : 0u;
    s[t] = v;
    __syncthreads();
    for (int off = 1; off < 256; off <<= 1) {
        unsigned x = (t >= off) ? s[t - off] : 0u;
        __syncthreads();
        s[t] += x;
        __syncthreads();
    }
    if (t < nb) base[t] = s[t] - v;
    if (t == 255) base[nb] = s[t];
}

// Pass C: full per-edge compute + direct scatter into sorted order
// (pairs only — 8B dword-aligned scattered stores; adding a second scattered
// store stream costs +30us, measured R13/R14).
__global__ __launch_bounds__(BSW, 4)
void k_scatter_full(const float* __restrict__ dr_vec,
                    const int* __restrict__ idx_i,
                    const int* __restrict__ idx_j,
                    const uint2* __restrict__ rcovZ,
                    const unsigned* __restrict__ ghist,
                    const unsigned* __restrict__ base,
                    uint2* __restrict__ pairs,
                    int n_edges, int nb) {
    __shared__ unsigned ofs[256];
    if ((int)threadIdx.x < nb)
        ofs[threadIdx.x] = base[threadIdx.x]
                         + ghist[(size_t)threadIdx.x * gridDim.x + blockIdx.x];
    __syncthreads();
    int nquad = n_edges >> 2;
    int tid = blockIdx.x * blockDim.x + threadIdx.x;
    int stride = gridDim.x * blockDim.x;
    for (int qd = tid; qd < nquad; qd += stride) {
        int e0 = qd << 2;
        float4 v0 = *reinterpret_cast<const float4*>(dr_vec + 3 * e0);
        float4 v1 = *reinterpret_cast<const float4*>(dr_vec + 3 * e0 + 4);
        float4 v2 = *reinterpret_cast<const float4*>(dr_vec + 3 * e0 + 8);
        float drq[4];
        drq[0] = sqrtf(v0.x*v0.x + v0.y*v0.y + v0.z*v0.z) / BOHR_F;
        drq[1] = sqrtf(v0.w*v0.w + v1.x*v1.x + v1.y*v1.y) / BOHR_F;
        drq[2] = sqrtf(v1.z*v1.z + v1.w*v1.w + v2.x*v2.x) / BOHR_F;
        drq[3] = sqrtf(v2.y*v2.y + v2.z*v2.z + v2.w*v2.w) / BOHR_F;
        int4 i4 = *reinterpret_cast<const int4*>(idx_i + e0);
        int4 j4 = *reinterpret_cast<const int4*>(idx_j + e0);
        int ia[4] = { i4.x, i4.y, i4.z, i4.w };
        int ja[4] = { j4.x, j4.y, j4.z, j4.w };
        uint2 RiZ[4], RjZ[4];
#pragma unroll
        for (int k = 0; k < 4; ++k) { RiZ[k] = rcovZ[ia[k]]; RjZ[k] = rcovZ[ja[k]]; }
#pragma unroll
        for (int k = 0; k < 4; ++k) {
            float rc = __uint_as_float(RiZ[k].x) + __uint_as_float(RjZ[k].x);
            float m = edge_m(drq[k], rc);
            unsigned q = (unsigned)(m * Q15_SCALE + 0.5f);
            if (q > 0x7FFFu) q = 0x7FFFu;
            unsigned dq = (unsigned)(drq[k] * DR_SCALE + 0.5f);
            if (dq > 0x7FFFu) dq = 0x7FFFu;
            unsigned w0 = ((unsigned)ia[k] << 15) | q;
            unsigned w1 = ((unsigned)ja[k] << 15) | dq;
            unsigned pos = atomicAdd(&ofs[ia[k] >> 9], 1u);
            pairs[pos] = make_uint2(w0, w1);
        }
    }
    // tail (same mapping as k_hist tail)
    for (int e = (nquad << 2) + tid; e < n_edges; e += stride) {
        float x = dr_vec[3*e], y = dr_vec[3*e+1], z = dr_vec[3*e+2];
        float dr = sqrtf(x*x + y*y + z*z) / BOHR_F;
        int i = idx_i[e], j = idx_j[e];
        uint2 RiZ = rcovZ[i], RjZ = rcovZ[j];
        float m = edge_m(dr, __uint_as_float(RiZ.x) + __uint_as_float(RjZ.x));
        unsigned q = (unsigned)(m * Q15_SCALE + 0.5f);
        if (q > 0x7FFFu) q = 0x7FFFu;
        unsigned dq = (unsigned)(dr * DR_SCALE + 0.5f);
        if (dq > 0x7FFFu) dq = 0x7FFFu;
        unsigned pos = atomicAdd(&ofs[i >> 9], 1u);
        pairs[pos] = make_uint2(((unsigned)i << 15) | q,
                                ((unsigned)j << 15) | dq);
    }
}

// Pass D: per-bucket LDS reduce -> cn; fused weights -> rec {w0..4, r4r2, Z, 0}
__global__ __launch_bounds__(512)
void k_reduce_weights(const uint2* __restrict__ pairs,
                      const unsigned* __restrict__ base,
                      const int* __restrict__ numbers,
                      const float* __restrict__ ref_cn_table,
                      const float* __restrict__ r4r2,
                      __half* __restrict__ rec,
                      int n_atoms) {
    __shared__ unsigned hist[512];
    hist[threadIdx.x] = 0;
    __syncthreads();
    int b = blockIdx.x;
    unsigned start = base[b];
    unsigned end   = base[b + 1];
    for (unsigned k = start + threadIdx.x; k < end; k += 512) {
        unsigned p = pairs[k].x;
        atomicAdd(&hist[(p >> 15) & 511], p & 0x7FFFu);
    }
    __syncthreads();
    int a = (b << 9) + threadIdx.x;
    if (a < n_atoms) {
        float c = (float)hist[threadIdx.x] * Q15_INV;
        int Z = numbers[a];
        float w[5];
        float s = 0.0f;
#pragma unroll
        for (int r = 0; r < 5; ++r) {
            float rcn = ref_cn_table[Z * 5 + r];
            float d = rcn - c;
            float wv = (rcn >= 0.0f) ? expf(-WF_F * d * d) : 0.0f;
            w[r] = wv;
            s += wv;
        }
        float den = s + EPS_F;
        __half* rr = rec + (size_t)a * 8;
#pragma unroll
        for (int r = 0; r < 5; ++r) rr[r] = __float2half(w[r] / den);
        rr[5] = __float2half(r4r2[Z]);
        rr[6] = __float2half((float)Z);
        rr[7] = __float2half(0.0f);
    }
}

// ---------------- energy (sorted, 8 edges/thread, Z from rec) ----------------
#define LOADC8(p, z) do { \
    const uint4* _cp = reinterpret_cast<const uint4*>(c6q + (size_t)(z) * 32); \
    p##0 = _cp[0]; p##1 = _cp[1]; } while (0)

__global__ __launch_bounds__(256)
void k_energy_sorted8r(const uint2* __restrict__ pairs,
                       const __half* __restrict__ rec,         // [N,8] halfs
                       const unsigned char* __restrict__ c6q,  // [95*95][32B]
                       double* __restrict__ e_acc,
                       int n_edges) {
    double local = 0.0;
    const uint4* recv = reinterpret_cast<const uint4*>(rec);
    int noct = n_edges >> 3;
    int tid = blockIdx.x * blockDim.x + threadIdx.x;
    int stride = gridDim.x * blockDim.x;
    for (int oc = tid; oc < noct; oc += stride) {
        int e0 = oc << 3;
        const uint4* pp = reinterpret_cast<const uint4*>(pairs + e0);
        uint4 p0 = pp[0], p1 = pp[1], p2 = pp[2], p3 = pp[3];
        unsigned iA = p0.x >> 15, jA = p0.y >> 15;
        unsigned iB = p0.z >> 15, jB = p0.w >> 15;
        unsigned iC = p1.x >> 15, jC = p1.y >> 15;
        unsigned iD = p1.z >> 15, jD = p1.w >> 15;
        unsigned iE = p2.x >> 15, jE = p2.y >> 15;
        unsigned iF = p2.z >> 15, jF = p2.w >> 15;
        unsigned iG = p3.x >> 15, jG = p3.y >> 15;
        unsigned iH = p3.z >> 15, jH = p3.w >> 15;
        float drA = (float)(p0.y & 0x7FFFu) * DR_INV;
        float drB = (float)(p0.w & 0x7FFFu) * DR_INV;
        float drC = (float)(p1.y & 0x7FFFu) * DR_INV;
        float drD = (float)(p1.w & 0x7FFFu) * DR_INV;
        float drE = (float)(p2.y & 0x7FFFu) * DR_INV;
        float drF = (float)(p2.w & 0x7FFFu) * DR_INV;
        float drG = (float)(p3.y & 0x7FFFu) * DR_INV;
        float drH = (float)(p3.w & 0x7FFFu) * DR_INV;
        // all 16 rec gathers issued together (independent addresses)
        uint4 RiA = recv[iA], RjA = recv[jA];
        uint4 RiB = recv[iB], RjB = recv[jB];
        uint4 RiC = recv[iC], RjC = recv[jC];
        uint4 RiD = recv[iD], RjD = recv[jD];
        uint4 RiE = recv[iE], RjE = recv[jE];
        uint4 RiF = recv[iF], RjF = recv[jF];
        uint4 RiG = recv[iG], RjG = recv[jG];
        uint4 RiH = recv[iH], RjH = recv[jH];
        // derive c6 row ids; c6 loads for edge X depend only on its own rec
        int zpA = zfromR(RjA) * NELEM + zfromR(RiA);
        int zpB = zfromR(RjB) * NELEM + zfromR(RiB);
        int zpC = zfromR(RjC) * NELEM + zfromR(RiC);
        int zpD = zfromR(RjD) * NELEM + zfromR(RiD);
        int zpE = zfromR(RjE) * NELEM + zfromR(RiE);
        int zpF = zfromR(RjF) * NELEM + zfromR(RiF);
        int zpG = zfromR(RjG) * NELEM + zfromR(RiG);
        int zpH = zfromR(RjH) * NELEM + zfromR(RiH);
        uint4 cA0, cA1;  LOADC8(cA, zpA);
        uint4 cB0, cB1;  LOADC8(cB, zpB);
        uint4 cC0, cC1;  LOADC8(cC, zpC);
        uint4 cD0, cD1;  LOADC8(cD, zpD);
        uint4 cE0, cE1;  LOADC8(cE, zpE);
        uint4 cF0, cF1;  LOADC8(cF, zpF);
        uint4 cG0, cG1;  LOADC8(cG, zpG);
        uint4 cH0, cH1;  LOADC8(cH, zpH);
        local += (double)edge_e8(drA, RiA, RjA, cA0, cA1);
        local += (double)edge_e8(drB, RiB, RjB, cB0, cB1);
        local += (double)edge_e8(drC, RiC, RjC, cC0, cC1);
        local += (double)edge_e8(drD, RiD, RjD, cD0, cD1);
        local += (double)edge_e8(drE, RiE, RjE, cE0, cE1);
        local += (double)edge_e8(drF, RiF, RjF, cF0, cF1);
        local += (double)edge_e8(drG, RiG, RjG, cG0, cG1);
        local += (double)edge_e8(drH, RiH, RjH, cH0, cH1);
    }
    // tail
    for (int e = (noct << 3) + tid; e < n_edges; e += stride) {
        uint2 pr = pairs[e];
        unsigned i = pr.x >> 15;
        unsigned j = pr.y >> 15;
        float dr = (float)(pr.y & 0x7FFFu) * DR_INV;
        uint4 Ri = recv[i];
        uint4 Rj = recv[j];
        int zp = zfromR(Rj) * NELEM + zfromR(Ri);
        const uint4* cp = reinterpret_cast<const uint4*>(c6q + (size_t)zp * 32);
        local += (double)edge_e8(dr, Ri, Rj, cp[0], cp[1]);
    }

    __shared__ double sdata[4];
    for (int off = 32; off > 0; off >>= 1)
        local += __shfl_down(local, off, 64);
    int lane = threadIdx.x & 63;
    int wid  = threadIdx.x >> 6;
    if (lane == 0) sdata[wid] = local;
    __syncthreads();
    if (threadIdx.x == 0) {
        double s = sdata[0] + sdata[1] + sdata[2] + sdata[3];
        atomicAdd(e_acc, s);
    }
}

// ---------------- atomic fallback path (small ws only) ----------------
__global__ __launch_bounds__(256)
void k_edges_cn_atomic(const float* __restrict__ dr_vec,
                       const int* __restrict__ idx_i,
                       const int* __restrict__ idx_j,
                       const uint2* __restrict__ rcovZ,
                       unsigned* __restrict__ cn_u32,
                       int n_edges) {
    int e = blockIdx.x * blockDim.x + threadIdx.x;
    if (e >= n_edges) return;
    float x = dr_vec[3 * e + 0];
    float y = dr_vec[3 * e + 1];
    float z = dr_vec[3 * e + 2];
    float dr = sqrtf(x * x + y * y + z * z) / BOHR_F;
    int i = idx_i[e];
    int j = idx_j[e];
    uint2 RiZ = rcovZ[i], RjZ = rcovZ[j];
    float m = edge_m(dr, __uint_as_float(RiZ.x) + __uint_as_float(RjZ.x));
    unsigned q = (unsigned)(m * CN_SCALE + 0.5f);
    if (q) atomicAdd(&cn_u32[i], q);
}

__global__ __launch_bounds__(256)
void k_atom_weights_rec(const unsigned* __restrict__ cn_u32,
                        const int* __restrict__ numbers,
                        const float* __restrict__ ref_cn_table,
                        const float* __restrict__ r4r2,
                        __half* __restrict__ rec,
                        int n_atoms) {
    int a = blockIdx.x * blockDim.x + threadIdx.x;
    if (a >= n_atoms) return;
    float c = (float)cn_u32[a] * CN_INV;
    int Z = numbers[a];
    float w[5];
    float s = 0.0f;
#pragma unroll
    for (int r = 0; r < 5; ++r) {
        float rcn = ref_cn_table[Z * 5 + r];
        float d = rcn - c;
        float wv = (rcn >= 0.0f) ? expf(-WF_F * d * d) : 0.0f;
        w[r] = wv;
        s += wv;
    }
    float den = s + EPS_F;
    __half* rr = rec + (size_t)a * 8;
#pragma unroll
    for (int r = 0; r < 5; ++r) rr[r] = __float2half(w[r] / den);
    rr[5] = __float2half(r4r2[Z]);
    rr[6] = __float2half((float)Z);
    rr[7] = __float2half(0.0f);
}

__global__ __launch_bounds__(256)
void k_energy_unsorted(const float* __restrict__ dr_vec,
                       const int* __restrict__ idx_i,
                       const int* __restrict__ idx_j,
                       const __half* __restrict__ rec,
                       const unsigned char* __restrict__ c6q,
                       double* __restrict__ e_acc,
                       int n_edges) {
    double local = 0.0;
    const uint4* recv = reinterpret_cast<const uint4*>(rec);
    int tid = blockIdx.x * blockDim.x + threadIdx.x;
    int stride = gridDim.x * blockDim.x;
    for (int e = tid; e < n_edges; e += stride) {
        float x = dr_vec[3*e], y = dr_vec[3*e+1], z = dr_vec[3*e+2];
        float dr = sqrtf(x*x + y*y + z*z) / BOHR_F;
        int i = idx_i[e], j = idx_j[e];
        uint4 Ri = recv[i];
        uint4 Rj = recv[j];
        int zp = zfromR(Rj) * NELEM + zfromR(Ri);
        const uint4* cp = reinterpret_cast<const uint4*>(c6q + (size_t)zp * 32);
        local += (double)edge_e8(dr, Ri, Rj, cp[0], cp[1]);
    }
    __shared__ double sdata[4];
    for (int off = 32; off > 0; off >>= 1)
        local += __shfl_down(local, off, 64);
    int lane = threadIdx.x & 63;
    int wid  = threadIdx.x >> 6;
    if (lane == 0) sdata[wid] = local;
    __syncthreads();
    if (threadIdx.x == 0) {
        double s = sdata[0] + sdata[1] + sdata[2] + sdata[3];
        atomicAdd(e_acc, s);
    }
}

__global__ void k_finalize(const double* __restrict__ e_acc,
                           float* __restrict__ out) {
    out[0] = (float)(e_acc[0] * HA_D);
}

static inline size_t a16(size_t x) { return (x + 15) & ~(size_t)15; }

extern "C" void kernel_launch(void* const* d_in, const int* in_sizes, int n_in,
                              void* d_out, int out_size, void* d_ws, size_t ws_size,
                              hipStream_t stream) {
    const float* dr_vec      = (const float*)d_in[0];
    const float* ref_cn_tab  = (const float*)d_in[1];
    const float* ref_c6_tab  = (const float*)d_in[2];
    const float* r4r2        = (const float*)d_in[3];
    const float* rcov        = (const float*)d_in[4];
    const int*   numbers     = (const int*)d_in[5];
    const int*   idx         = (const int*)d_in[6];

    int n_atoms = in_sizes[5];
    int n_edges = in_sizes[6] / 2;
    const int* idx_i = idx;
    const int* idx_j = idx + n_edges;

    const int BS = 256;
    int nb = (n_atoms + 511) >> 9;
    int nrows = NELEM * NELEM;

    char* ws = (char*)d_ws;
    double* e_acc = (double*)ws;

    // common prefix: [e_acc 16][rec N*16B][c6q rows*32B][rcovZ N*8]
    size_t off_rec = 16;
    size_t off_c6q = a16(off_rec + (size_t)n_atoms * 8 * 2);
    size_t off_rcZ = a16(off_c6q + (size_t)nrows * 32);
    size_t off_var = a16(off_rcZ + (size_t)n_atoms * 8);

    // sort path: [pairs 8E][ghist nb*NBLK][tot][base]
    size_t s_pairs  = off_var;
    size_t s_ghist  = a16(s_pairs + (size_t)n_edges * 8);
    size_t s_tot    = a16(s_ghist + (size_t)nb * NBLK * 4);
    size_t s_base   = a16(s_tot + (size_t)nb * 4);
    size_t need_s   = s_base + (size_t)(nb + 1) * 4;

    // atomic path: [cn N*4]
    size_t a_cn   = off_var;

    int grid_r  = (nrows + BS - 1) / BS;
    int grid_a  = (n_atoms + BS - 1) / BS;
    int noct    = n_edges >> 3;
    int grid_o  = (noct + BS - 1) / BS;
    if (grid_o < 1) grid_o = 1;
    if (grid_o > 8192) grid_o = 8192;
    int grid_e1 = (n_edges + BS - 1) / BS;
    if (grid_e1 > 8192) grid_e1 = 8192;

    __half*        rec   = (__half*)(ws + off_rec);
    unsigned char* c6q   = (unsigned char*)(ws + off_c6q);
    uint2*         rcovZ = (uint2*)(ws + off_rcZ);

    k_prep_c6u8<<<grid_r, BS, 0, stream>>>(ref_c6_tab, c6q, nrows);
    k_prep_atom<<<grid_a, BS, 0, stream>>>(numbers, rcov, rcovZ, n_atoms);

    bool sortable = (n_atoms <= (1 << 17)) && (nb <= 256);

    if (sortable && ws_size >= need_s) {
        uint2*    pairs   = (uint2*)(ws + s_pairs);
        unsigned* ghist   = (unsigned*)(ws + s_ghist);
        unsigned* totals  = (unsigned*)(ws + s_tot);
        unsigned* base    = (unsigned*)(ws + s_base);

        hipMemsetAsync(d_ws, 0, 16, stream);   // e_acc only

        k_hist<<<NBLK, BSW, 0, stream>>>(idx_i, ghist, n_edges, nb);
        k_scan_bucket<<<nb, NBLK, 0, stream>>>(ghist, totals);
        k_scan_base<<<1, 256, 0, stream>>>(totals, base, nb);
        k_scatter_full<<<NBLK, BSW, 0, stream>>>(dr_vec, idx_i, idx_j, rcovZ,
            ghist, base, pairs, n_edges, nb);
        k_reduce_weights<<<nb, 512, 0, stream>>>(pairs, base, numbers,
            ref_cn_tab, r4r2, rec, n_atoms);
        k_energy_sorted8r<<<grid_o, BS, 0, stream>>>(pairs, rec, c6q, e_acc,
                                                     n_edges);
    } else {
        unsigned* cn_u32 = (unsigned*)(ws + a_cn);
        hipMemsetAsync(d_ws, 0, 16, stream);
        hipMemsetAsync(cn_u32, 0, (size_t)n_atoms * 4, stream);

        int grid_e = (n_edges + BS - 1) / BS;
        k_edges_cn_atomic<<<grid_e, BS, 0, stream>>>(dr_vec, idx_i, idx_j,
            rcovZ, cn_u32, n_edges);
        k_atom_weights_rec<<<grid_a, BS, 0, stream>>>(cn_u32, numbers,
            ref_cn_tab, r4r2, rec, n_atoms);
        k_energy_unsorted<<<grid_e1, BS, 0, stream>>>(dr_vec, idx_i, idx_j,
            rec, c6q, e_acc, n_edges);
    }

    k_finalize<<<1, 1, 0, stream>>>(e_acc, (float*)d_out);
}